// Round 14
// baseline (154.926 us; speedup 1.0000x reference)
//
#include <hip/hip_runtime.h>
#include <cmath>

// Kalman_Smooth_Gradient: B=4096 seqs, T=128 steps, 6-state EKF + RTS + loss.
// Round 14: exact 3x 2-state factorization (r9) +
//   fwd_kernel:  192 blocks x 64 thr. Stages z(f) for 64 seqs into LDS with
//     lanes-along-t loads (12-line gathers; kills the ztrans dispatch), then
//     the serial forward filter; hist4/hist1 coalesced stores.
//   bwd_kernel:  192 blocks x 1024 thr (16 waves = 16 chunks x 64 chains,
//     4 waves/SIMD). The backward RTS recurrence is affine:
//       s(n) = G_n s(n+1) + b_n ; P(n) = G_n P(n+1) G_n^T + C_n  (9 floats).
//     Phase 1: build + compose within-chunk suffix ops from hist, keeping a
//       4-float loss projection (G row0, b0, C00) per step in registers.
//     Phase 2: Kogge-Stone suffix scan of chunk ops in LDS.
//     Phase 3: chunk-entry state from neighbor suffix applied to terminal;
//       apply projections (+ LDS z) -> a, a*e^2; wave-reduce + atomic.
//   det_kernel: sum ax*ay*at over 126*B coalesced triples.

namespace {

constexpr int B = 4096;
constexpr int T = 128;
constexpr int NT = B * 3;           // 12288 filter chains
constexpr int TRIPLES = 126 * B;    // det terms, n = 2..127
constexpr float DTc     = 1.0f / 120.0f;
constexpr float TWO_PIc = 6.28318530717958647692f;
constexpr float PI_1_5  = 4.71238898038468985769f;
constexpr float INV_2PI = 0.15915494309189533577f;

__device__ __forceinline__ float frcp(float x) { return __builtin_amdgcn_rcpf(x); }

__device__ __forceinline__ float fast_tanh(float x) {
  float e = __expf(2.0f * x);
  return 1.0f - 2.0f * frcp(e + 1.0f);
}
__device__ __forceinline__ float sigmoidf(float x) {
  return frcp(1.0f + __expf(-x));
}

// ---------------------------------------------------------------------------
// fwd_kernel: one wave per block; block = (filter f) x (64 seqs).
// hist4: [T][NT] float4 (p,v,P00,P01); hist1: [T][NT] float P11.
// ---------------------------------------------------------------------------
__global__ __launch_bounds__(64, 1) void fwd_kernel(
    const float* __restrict__ params, const float* __restrict__ covp,
    const float* __restrict__ init_states, const float* __restrict__ z,
    float4* __restrict__ hist4, float* __restrict__ hist1) {
  const int lane = threadIdx.x;
  const int blk = blockIdx.x;
  const int f = blk >> 6;           // 0=x, 1=y, 2=theta (wave-uniform)
  const int g = blk & 63;
  const int seq = g * 64 + lane;
  const int fi = f * B + seq;

  __shared__ float zl[128 * 65];    // [t][seq-in-group], stride 65 (bank-safe)

  // ---- stage z: lanes-along-t (12-line gathers), writes bank-conflict-free
  {
#pragma unroll 4
    for (int s2 = 0; s2 < 64; s2++) {
      const float* zb = z + (size_t)(g * 64 + s2) * (T * 3) + f;
      const float v0 = zb[(size_t)lane * 3];
      const float v1 = zb[(size_t)(64 + lane) * 3];
      zl[lane * 65 + s2] = v0;
      zl[(64 + lane) * 65 + s2] = v1;
    }
  }
  __syncthreads();

  // ---- shared scalars ----
  const float friction = (fast_tanh(params[0]) + 1.0f) * 0.01f;
  const float damping  = (fast_tanh(params[1]) + 1.0f) * 0.01f;
  float cp[7];
#pragma unroll
  for (int i = 0; i < 7; i++) cp[i] = sigmoidf(covp[i]);
  const float dcoef = 1.0f - DTc * damping;
  const bool isTH = (f == 2);
  const float q0 = isTH ? cp[5] : cp[3];
  const float q1 = isTH ? cp[6] : cp[4];
  const float r  = cp[f];

  const int pidx = (f == 0) ? 0 : (f == 1) ? 1 : 4;
  const int vidx = (f == 0) ? 2 : (f == 1) ? 3 : 5;
  float p = init_states[seq * 6 + pidx];
  float v = init_states[seq * 6 + vidx];
  float P00 = 0.01f, P01 = 0.0f, P11 = 0.01f;

#pragma unroll 8
  for (int t = 0; t < T; t++) {
    const float zc = zl[t * 65 + lane];

    float gg, tv;
    if (!isTH) {
      const float th = fast_tanh(100.0f * v);
      tv = v - DTc * (damping * v + friction * th);
      gg = 1.0f - DTc * (damping + 100.0f * friction * (1.0f - th * th));
    } else {
      tv = dcoef * v;
      gg = dcoef;
    }
    const float tp = p + DTc * v;
    const float u = P01 + DTc * P11;
    const float Pp00 = P00 + DTc * P01 + DTc * u + q0;
    const float Pp01 = gg * u;
    const float Pp11 = gg * (gg * P11) + q1;
    const float iS = frcp(Pp00 + r);
    const float K0 = Pp00 * iS;
    const float K1 = Pp01 * iS;
    float e = zc - tp;
    if (isTH) e = e - TWO_PIc * rintf(e * INV_2PI);  // _wrap
    p = tp + K0 * e;
    v = tv + K1 * e;
    const float om = 1.0f - K0;
    P00 = om * Pp00;
    P01 = om * Pp01;
    P11 = Pp11 - K1 * Pp01;

    hist4[(size_t)t * NT + fi] = make_float4(p, v, P00, P01);
    hist1[(size_t)t * NT + fi] = P11;
  }
}

// ---------------------------------------------------------------------------
// bwd_kernel: 16 waves = 16 chunks x 64 chains. Chunk c covers backward steps
// n in [8c, 8c+7] (c=15: [120,126]). aqA[(n*3+f)*B + seq] = a (n = 2..127).
// ---------------------------------------------------------------------------
__global__ __launch_bounds__(1024, 1) void bwd_kernel(
    const float* __restrict__ params, const float* __restrict__ covp,
    const float* __restrict__ z,
    const float4* __restrict__ hist4, const float* __restrict__ hist1,
    float* __restrict__ aqA, float* __restrict__ out) {
  const int tid = threadIdx.x;
  const int c = tid >> 6;           // chunk / wave id (wave-uniform)
  const int j = tid & 63;           // chain lane
  const int blk = blockIdx.x;
  const int f = blk >> 6;
  const int g = blk & 63;
  const int seq = g * 64 + j;
  const int fi = f * B + seq;

  __shared__ float ops[16 * 64 * 9];   // 36 KB
  __shared__ float zl[128 * 65];       // 33.3 KB

  // ---- stage z: wave c loads 4 seqs, lanes-along-t ----
  {
#pragma unroll
    for (int s2 = 0; s2 < 4; s2++) {
      const int sl_ = c * 4 + s2;
      const float* zb = z + (size_t)(g * 64 + sl_) * (T * 3) + f;
      const float v0 = zb[(size_t)j * 3];
      const float v1 = zb[(size_t)(64 + j) * 3];
      zl[j * 65 + sl_] = v0;
      zl[(64 + j) * 65 + sl_] = v1;
    }
  }

  // ---- shared scalars ----
  const float friction = (fast_tanh(params[0]) + 1.0f) * 0.01f;
  const float damping  = (fast_tanh(params[1]) + 1.0f) * 0.01f;
  float cp[7];
#pragma unroll
  for (int i = 0; i < 7; i++) cp[i] = sigmoidf(covp[i]);
  const float dcoef = 1.0f - DTc * damping;
  const bool isTH = (f == 2);
  const float q0 = isTH ? cp[5] : cp[3];
  const float q1 = isTH ? cp[6] : cp[4];
  const float r  = cp[f];

  // ---- phase 1: build within-chunk suffix op + per-step loss projections ---
  float qG00, qG01, qG10, qG11, qb0, qb1, qC00, qC01, qC11;
  qG00 = qG01 = qG10 = qG11 = qb0 = qb1 = qC00 = qC01 = qC11 = 0.0f;
  float prG0[8], prG1[8], prB[8], prC[8];
  bool started = false;

#pragma unroll
  for (int i = 0; i < 8; i++) {
    const int n = 8 * c + 7 - i;
    if (n > 126) continue;          // only (c==15, i==0): wave-uniform
    const float4 h4 = hist4[(size_t)n * NT + fi];
    const float f11 = hist1[(size_t)n * NT + fi];
    const float fp = h4.x, fv = h4.y, f00 = h4.z, f01 = h4.w;

    float gg, tv;
    if (!isTH) {
      const float th = fast_tanh(100.0f * fv);
      tv = fv - DTc * (damping * fv + friction * th);
      gg = 1.0f - DTc * (damping + 100.0f * friction * (1.0f - th * th));
    } else {
      tv = dcoef * fv;
      gg = dcoef;
    }
    const float tp = fp + DTc * fv;
    const float u = f01 + DTc * f11;
    const float Pp00 = f00 + DTc * f01 + DTc * u + q0;
    const float Pp01 = gg * u;
    const float Pp11 = gg * (gg * f11) + q1;

    const float idet = frcp(Pp00 * Pp11 - Pp01 * Pp01);
    const float W01 = DTc * f00 + gg * f01;
    const float W11 = DTc * f01 + gg * f11;
    const float G00 = (f00 * Pp11 - W01 * Pp01) * idet;
    const float G01 = (W01 * Pp00 - f00 * Pp01) * idet;
    const float G10 = (f01 * Pp11 - W11 * Pp01) * idet;
    const float G11 = (W11 * Pp00 - f01 * Pp01) * idet;
    const float b0 = fp - (G00 * tp + G01 * tv);
    const float b1 = fv - (G10 * tp + G11 * tv);
    // C = Pf - G Pp G^T
    const float Y00 = G00 * Pp00 + G01 * Pp01;
    const float Y01 = G00 * Pp01 + G01 * Pp11;
    const float Y10 = G10 * Pp00 + G11 * Pp01;
    const float Y11 = G10 * Pp01 + G11 * Pp11;
    const float C00 = f00 - (Y00 * G00 + Y01 * G01);
    const float C01 = f01 - (Y00 * G10 + Y01 * G11);
    const float C11 = f11 - (Y10 * G10 + Y11 * G11);

    if (!started) {
      qG00 = G00; qG01 = G01; qG10 = G10; qG11 = G11;
      qb0 = b0; qb1 = b1; qC00 = C00; qC01 = C01; qC11 = C11;
      started = true;
    } else {
      // q' = op_n o q (apply q first, then op_n)
      const float nG00 = G00 * qG00 + G01 * qG10;
      const float nG01 = G00 * qG01 + G01 * qG11;
      const float nG10 = G10 * qG00 + G11 * qG10;
      const float nG11 = G10 * qG01 + G11 * qG11;
      const float nb0 = G00 * qb0 + G01 * qb1 + b0;
      const float nb1 = G10 * qb0 + G11 * qb1 + b1;
      const float t00 = G00 * qC00 + G01 * qC01;
      const float t01 = G00 * qC01 + G01 * qC11;
      const float t10 = G10 * qC00 + G11 * qC01;
      const float t11 = G10 * qC01 + G11 * qC11;
      const float nC00 = t00 * G00 + t01 * G01 + C00;
      const float nC01 = t00 * G10 + t01 * G11 + C01;
      const float nC11 = t10 * G10 + t11 * G11 + C11;
      qG00 = nG00; qG01 = nG01; qG10 = nG10; qG11 = nG11;
      qb0 = nb0; qb1 = nb1; qC00 = nC00; qC01 = nC01; qC11 = nC11;
    }
    const int idx = 7 - i;   // = n - 8c, const per unrolled iter
    prG0[idx] = qG00; prG1[idx] = qG01; prB[idx] = qb0; prC[idx] = qC00;
  }

  // write own chunk op to LDS
  float* __restrict__ mo = &ops[(c * 64 + j) * 9];
  mo[0] = qG00; mo[1] = qG01; mo[2] = qG10; mo[3] = qG11;
  mo[4] = qb0;  mo[5] = qb1;
  mo[6] = qC00; mo[7] = qC01; mo[8] = qC11;
  __syncthreads();

  // ---- phase 2: Kogge-Stone inclusive suffix scan over 16 chunk ops ----
#pragma unroll
  for (int rr = 1; rr < 16; rr <<= 1) {
    float pv[9];
    const bool act = (c + rr) < 16;
    if (act) {
      const float* __restrict__ pp = &ops[((c + rr) * 64 + j) * 9];
#pragma unroll
      for (int k = 0; k < 9; k++) pv[k] = pp[k];
    }
    __syncthreads();
    if (act) {
      // q = q o pv (apply pv first, then q)
      const float nG00 = qG00 * pv[0] + qG01 * pv[2];
      const float nG01 = qG00 * pv[1] + qG01 * pv[3];
      const float nG10 = qG10 * pv[0] + qG11 * pv[2];
      const float nG11 = qG10 * pv[1] + qG11 * pv[3];
      const float nb0 = qG00 * pv[4] + qG01 * pv[5] + qb0;
      const float nb1 = qG10 * pv[4] + qG11 * pv[5] + qb1;
      const float t00 = qG00 * pv[6] + qG01 * pv[7];
      const float t01 = qG00 * pv[7] + qG01 * pv[8];
      const float t10 = qG10 * pv[6] + qG11 * pv[7];
      const float t11 = qG10 * pv[7] + qG11 * pv[8];
      const float nC00 = t00 * qG00 + t01 * qG01 + qC00;
      const float nC01 = t00 * qG10 + t01 * qG11 + qC01;
      const float nC11 = t10 * qG10 + t11 * qG11 + qC11;
      qG00 = nG00; qG01 = nG01; qG10 = nG10; qG11 = nG11;
      qb0 = nb0; qb1 = nb1; qC00 = nC00; qC01 = nC01; qC11 = nC11;
    }
    mo[0] = qG00; mo[1] = qG01; mo[2] = qG10; mo[3] = qG11;
    mo[4] = qb0;  mo[5] = qb1;
    mo[6] = qC00; mo[7] = qC01; mo[8] = qC11;
    __syncthreads();
  }

  // ---- phase 3: entry state + apply projections + loss ----
  const float4 ht = hist4[(size_t)(T - 1) * NT + fi];
  const float ht1 = hist1[(size_t)(T - 1) * NT + fi];
  float sE0, sE1, PE00, PE01, PE11;
  float qacc = 0.0f;

  if (c == 15) {
    sE0 = ht.x; sE1 = ht.y; PE00 = ht.z; PE01 = ht.w; PE11 = ht1;
    // terminal loss term n = T-1 (smoothed == filtered)
    const float a = PE00 + r;
    float e = zl[(T - 1) * 65 + j] - sE0;
    if (isTH) {
      if (e >  PI_1_5) e -= TWO_PIc;
      if (e < -PI_1_5) e += TWO_PIc;
    }
    qacc = a * e * e;
    aqA[(size_t)((T - 1) * 3 + f) * B + seq] = a;
  } else {
    // exclusive suffix = inclusive suffix of chunk c+1, applied to terminal
    const float* __restrict__ pp = &ops[((c + 1) * 64 + j) * 9];
    const float eg0 = pp[0], eg1 = pp[1], eg2 = pp[2], eg3 = pp[3];
    sE0 = eg0 * ht.x + eg1 * ht.y + pp[4];
    sE1 = eg2 * ht.x + eg3 * ht.y + pp[5];
    const float Y00 = eg0 * ht.z + eg1 * ht.w;
    const float Y01 = eg0 * ht.w + eg1 * ht1;
    const float Y10 = eg2 * ht.z + eg3 * ht.w;
    const float Y11 = eg2 * ht.w + eg3 * ht1;
    PE00 = Y00 * eg0 + Y01 * eg1 + pp[6];
    PE01 = Y00 * eg2 + Y01 * eg3 + pp[7];
    PE11 = Y10 * eg2 + Y11 * eg3 + pp[8];
  }

#pragma unroll
  for (int i = 0; i < 8; i++) {
    const int n = 8 * c + 7 - i;
    if (n > 126 || n < 2) continue;   // wave-uniform skips (c==15 / c==0)
    const int idx = 7 - i;
    const float g0 = prG0[idx], g1 = prG1[idx];
    const float s0n = g0 * sE0 + g1 * sE1 + prB[idx];
    const float P00n = g0 * g0 * PE00 + 2.0f * g0 * g1 * PE01 +
                       g1 * g1 * PE11 + prC[idx];
    const float a = P00n + r;
    float e = zl[n * 65 + j] - s0n;
    if (isTH) {
      if (e >  PI_1_5) e -= TWO_PIc;
      if (e < -PI_1_5) e += TWO_PIc;
    }
    qacc += a * e * e;
    aqA[(size_t)(n * 3 + f) * B + seq] = a;
  }

  // ---- wave reduce + one atomic per wave ----
#pragma unroll
  for (int off = 32; off > 0; off >>= 1) qacc += __shfl_down(qacc, off);
  if (j == 0) atomicAdd(out, qacc);
}

// ---------------------------------------------------------------------------
// det_kernel: sum over (seq, n=2..127) of ax*ay*at. Coalesced triple loads.
// ---------------------------------------------------------------------------
__global__ __launch_bounds__(256, 4) void det_kernel(
    const float* __restrict__ aqA, float* __restrict__ out) {
  const int tid0 = blockIdx.x * 256 + threadIdx.x;
  const int stride = gridDim.x * 256;
  float part = 0.0f;
  for (int idx = tid0; idx < TRIPLES; idx += stride) {
    const int n2 = 2 + (idx >> 12);       // idx / B
    const int seq = idx & (B - 1);
    const float a0 = aqA[(size_t)(n2 * 3 + 0) * B + seq];
    const float a1 = aqA[(size_t)(n2 * 3 + 1) * B + seq];
    const float a2 = aqA[(size_t)(n2 * 3 + 2) * B + seq];
    part += a0 * a1 * a2;
  }
#pragma unroll
  for (int off = 32; off > 0; off >>= 1) part += __shfl_down(part, off);
  __shared__ float red[4];
  if ((threadIdx.x & 63) == 0) red[threadIdx.x >> 6] = part;
  __syncthreads();
  if (threadIdx.x == 0) atomicAdd(out, red[0] + red[1] + red[2] + red[3]);
}

}  // namespace

extern "C" void kernel_launch(void* const* d_in, const int* in_sizes, int n_in,
                              void* d_out, int out_size, void* d_ws, size_t ws_size,
                              hipStream_t stream) {
  const float* params      = (const float*)d_in[0];
  const float* covp        = (const float*)d_in[1];
  const float* init_states = (const float*)d_in[2];
  const float* z           = (const float*)d_in[3];
  float* out = (float*)d_out;

  const size_t hist4B = (size_t)T * NT * sizeof(float4);   // 25.2 MB
  const size_t hist1B = (size_t)T * NT * sizeof(float);    //  6.3 MB
  const size_t aqB    = (size_t)T * 3 * B * sizeof(float); //  6.3 MB
  const size_t needBytes = hist4B + hist1B + aqB;          // 37.8 MB

  hipMemsetAsync(d_out, 0, sizeof(float), stream);

  if (ws_size >= needBytes) {
    float4* hist4 = (float4*)d_ws;
    float*  hist1 = (float*)((char*)d_ws + hist4B);
    float*  aqA   = (float*)((char*)d_ws + hist4B + hist1B);
    fwd_kernel<<<192, 64, 0, stream>>>(params, covp, init_states, z,
                                       hist4, hist1);
    bwd_kernel<<<192, 1024, 0, stream>>>(params, covp, z, hist4, hist1,
                                         aqA, out);
    det_kernel<<<504, 256, 0, stream>>>(aqA, out);
  }
}

// Round 15
// 122.303 us; speedup vs baseline: 1.2667x; 1.2667x over previous
//
#include <hip/hip_runtime.h>
#include <cmath>

// Kalman_Smooth_Gradient: B=4096 seqs, T=128 steps, 6-state EKF + RTS + loss.
// Round 15: r11's single fused kernel (known-good 62us: 64 blocks x 192 thr,
// three independent 2-state filters per seq, serial fwd+bwd per chain, block-
// local det epilogue) + r13's z fix applied IN-KERNEL: stage the block's
// contiguous 96 KB z slab into LDS via coalesced float4 loads (32-iter
// prologue, conflict-free stride-65 writes), so all fwd/bwd z reads are LDS.
// Removes the ztrans dispatch and all z global-gather stalls.

namespace {

constexpr int B = 4096;
constexpr int T = 128;
constexpr int SPB = 64;             // seqs per block
constexpr int NBLK = B / SPB;       // 64 blocks
constexpr int NTH = 3 * SPB;        // 192 threads per block
constexpr int NT = B * 3;           // 12288 filter chains
constexpr float DTc     = 1.0f / 120.0f;
constexpr float TWO_PIc = 6.28318530717958647692f;
constexpr float PI_1_5  = 4.71238898038468985769f;
constexpr float INV_2PI = 0.15915494309189533577f;

__device__ __forceinline__ float frcp(float x) { return __builtin_amdgcn_rcpf(x); }

__device__ __forceinline__ float fast_tanh(float x) {
  float e = __expf(2.0f * x);
  return 1.0f - 2.0f * frcp(e + 1.0f);
}
__device__ __forceinline__ float sigmoidf(float x) {
  return frcp(1.0f + __expf(-x));
}

// ---------------------------------------------------------------------------
// Fused kernel. hist4: [T][NT] float4 (p,v,P00,P01); hist1: [T][NT] float P11;
// aq: [T][NT] float2 (a, a*e^2), valid n = 2..T-1.
// LDS zl layout: zl[(t*3+k)*65 + s]  (s = seq-in-block; stride 65 bank-safe).
// ---------------------------------------------------------------------------
__global__ __launch_bounds__(NTH, 1) void fused_kernel(
    const float* __restrict__ params, const float* __restrict__ covp,
    const float* __restrict__ init_states, const float* __restrict__ z,
    float4* __restrict__ hist4, float* __restrict__ hist1,
    float2* __restrict__ aq, float* __restrict__ out) {
  const int tid = threadIdx.x;
  const int f = tid >> 6;           // filter 0=x,1=y,2=theta (wave-uniform)
  const int sb = tid & 63;          // seq within block
  const int blk = blockIdx.x;
  const int seq = blk * SPB + sb;
  const int gid = blk * NTH + tid;  // global filter-thread id

  __shared__ float zl[384 * 65];    // 99840 B
  __shared__ float red[3];

  // ---- stage z slab: 24576 floats, coalesced float4 loads ----
  // global float idx within slab = s2*384 + (t*3+k); thread tid, iter i loads
  // idx = i*768 + tid*4 .. +3  ->  s2 = i*2 + tid/96, col = (tid%96)*4 + e.
  // (col+e never crosses 384, so s2 is constant per float4.)
  {
    const float* __restrict__ zslab = z + (size_t)blk * SPB * (T * 3);
    const int q = (tid >= 96) ? 1 : 0;
    const int col = (tid - q * 96) * 4;
#pragma unroll 4
    for (int i = 0; i < 32; i++) {
      const int s2 = i * 2 + q;
      const float4 v4 = *(const float4*)(zslab + (size_t)i * 768 + tid * 4);
      zl[(col + 0) * 65 + s2] = v4.x;
      zl[(col + 1) * 65 + s2] = v4.y;
      zl[(col + 2) * 65 + s2] = v4.z;
      zl[(col + 3) * 65 + s2] = v4.w;
    }
  }
  __syncthreads();

  // ---- shared scalars ----
  const float friction = (fast_tanh(params[0]) + 1.0f) * 0.01f;
  const float damping  = (fast_tanh(params[1]) + 1.0f) * 0.01f;
  float cp[7];
#pragma unroll
  for (int i = 0; i < 7; i++) cp[i] = sigmoidf(covp[i]);
  const float dcoef = 1.0f - DTc * damping;
  const bool isTH = (f == 2);                 // wave-uniform branch
  const float q0 = isTH ? cp[5] : cp[3];
  const float q1 = isTH ? cp[6] : cp[4];
  const float r  = cp[f];

  // ---- init ----
  const int pidx = (f == 0) ? 0 : (f == 1) ? 1 : 4;
  const int vidx = (f == 0) ? 2 : (f == 1) ? 3 : 5;
  float p = init_states[seq * 6 + pidx];
  float v = init_states[seq * 6 + vidx];
  float P00 = 0.01f, P01 = 0.0f, P11 = 0.01f;

  // =========================== forward ===========================
#pragma unroll 8
  for (int t = 0; t < T; t++) {
    const float zc = zl[(t * 3 + f) * 65 + sb];

    float g, tv;
    if (!isTH) {
      const float th = fast_tanh(100.0f * v);
      tv = v - DTc * (damping * v + friction * th);
      g = 1.0f - DTc * (damping + 100.0f * friction * (1.0f - th * th));
    } else {
      tv = dcoef * v;
      g = dcoef;
    }
    const float tp = p + DTc * v;
    const float u = P01 + DTc * P11;
    const float Pp00 = P00 + DTc * P01 + DTc * u + q0;
    const float Pp01 = g * u;
    const float Pp11 = g * (g * P11) + q1;
    const float iS = frcp(Pp00 + r);
    const float K0 = Pp00 * iS;
    const float K1 = Pp01 * iS;
    float e = zc - tp;
    if (isTH) e = e - TWO_PIc * rintf(e * INV_2PI);  // _wrap
    p = tp + K0 * e;
    v = tv + K1 * e;
    const float om = 1.0f - K0;
    P00 = om * Pp00;
    P01 = om * Pp01;
    P11 = Pp11 - K1 * Pp01;

    hist4[(size_t)t * NT + gid] = make_float4(p, v, P00, P01);
    hist1[(size_t)t * NT + gid] = P11;
  }

  // ---- terminal loss term n = T-1 (smoothed == filtered) ----
  {
    const float zlv = zl[((T - 1) * 3 + f) * 65 + sb];
    float e = zlv - p;
    if (isTH) {
      if (e >  PI_1_5) e -= TWO_PIc;
      if (e < -PI_1_5) e += TWO_PIc;
    }
    const float a = P00 + r;
    aq[(size_t)(T - 1) * NT + gid] = make_float2(a, a * e * e);
  }

  // =========================== backward ===========================
  float sp_ = p, sv_ = v, Ps00 = P00, Ps01 = P01, Ps11 = P11;

  // depth-8 rolling prefetch of hist; iteration i -> n = 126 - i; padded to
  // 128 iters (n = 126..-1); n < 2 iterations compute garbage, never store.
  float4 h4b[8];
  float h1b[8];
#pragma unroll
  for (int i = 0; i < 8; i++) {
    const int n2 = 126 - i;
    h4b[i] = hist4[(size_t)n2 * NT + gid];
    h1b[i] = hist1[(size_t)n2 * NT + gid];
  }

#pragma unroll 8
  for (int i = 0; i < 128; i++) {
    const int n = 126 - i;
    const int sl = i & 7;
    const float4 h4 = h4b[sl];
    const float h1 = h1b[sl];
    const int nz = (n < 2) ? 2 : n;
    const float zn_ = zl[(nz * 3 + f) * 65 + sb];
    const int nf = (n >= 10) ? (n - 8) : 2;  // clamped prefetch target
    h4b[sl] = hist4[(size_t)nf * NT + gid];
    h1b[sl] = hist1[(size_t)nf * NT + gid];

    const float fp = h4.x, fv = h4.y, f00 = h4.z, f01 = h4.w, f11 = h1;

    float g, tv;
    if (!isTH) {
      const float th = fast_tanh(100.0f * fv);
      tv = fv - DTc * (damping * fv + friction * th);
      g = 1.0f - DTc * (damping + 100.0f * friction * (1.0f - th * th));
    } else {
      tv = dcoef * fv;
      g = dcoef;
    }
    const float tp = fp + DTc * fv;
    const float u = f01 + DTc * f11;
    const float Pp00 = f00 + DTc * f01 + DTc * u + q0;
    const float Pp01 = g * u;
    const float Pp11 = g * (g * f11) + q1;

    // G = P_f F^T Pp^{-1} (closed-form 2x2)
    const float idet = frcp(Pp00 * Pp11 - Pp01 * Pp01);
    const float W00 = f00, W01 = DTc * f00 + g * f01;
    const float W10 = f01, W11 = DTc * f01 + g * f11;
    const float G00 = (W00 * Pp11 - W01 * Pp01) * idet;
    const float G01 = (W01 * Pp00 - W00 * Pp01) * idet;
    const float G10 = (W10 * Pp11 - W11 * Pp01) * idet;
    const float G11 = (W11 * Pp00 - W10 * Pp01) * idet;

    const float ds0 = sp_ - tp, ds1 = sv_ - tv;
    const float np = fp + G00 * ds0 + G01 * ds1;
    const float nv = fv + G10 * ds0 + G11 * ds1;

    const float M00 = Ps00 - Pp00, M01 = Ps01 - Pp01, M11 = Ps11 - Pp11;
    const float GM00 = G00 * M00 + G01 * M01, GM01 = G00 * M01 + G01 * M11;
    const float GM10 = G10 * M00 + G11 * M01, GM11 = G10 * M01 + G11 * M11;
    Ps00 = f00 + GM00 * G00 + GM01 * G01;
    Ps01 = f01 + GM00 * G10 + GM01 * G11;
    Ps11 = f11 + GM10 * G10 + GM11 * G11;
    sp_ = np;
    sv_ = nv;

    if (n >= 2) {
      const float a = Ps00 + r;
      float e = zn_ - np;
      if (isTH) {
        if (e >  PI_1_5) e -= TWO_PIc;
        if (e < -PI_1_5) e += TWO_PIc;
      }
      aq[(size_t)n * NT + gid] = make_float2(a, a * e * e);
    }
  }

  __syncthreads();  // aq stores -> epilogue loads (same block/CU)

  // =========================== epilogue ===========================
  // 64 seqs x 126 loss terms (n=2..127) = 8064 pairs; 42 per thread.
  float part = 0.0f;
  const int base = blk * NTH;

  // depth-4 rolling prefetch; padded to 44 iters (guarded accumulate)
  float2 b0[4], b1[4], b2[4];
#pragma unroll
  for (int k = 0; k < 4; k++) {
    const int pi = tid + k * NTH;
    const size_t o = (size_t)(2 + (pi >> 6)) * NT + base + (pi & 63);
    b0[k] = aq[o];
    b1[k] = aq[o + 64];
    b2[k] = aq[o + 128];
  }

#pragma unroll 4
  for (int k = 0; k < 44; k++) {
    const int sl = k & 3;
    const float2 x0 = b0[sl];
    const float2 x1 = b1[sl];
    const float2 x2 = b2[sl];
    const int kf = (k + 4 < 42) ? (k + 4) : 41;  // clamped prefetch
    {
      const int pi = tid + kf * NTH;
      const size_t o = (size_t)(2 + (pi >> 6)) * NT + base + (pi & 63);
      b0[sl] = aq[o];
      b1[sl] = aq[o + 64];
      b2[sl] = aq[o + 128];
    }
    if (k < 42) part += x0.x * x1.x * x2.x + (x0.y + x1.y + x2.y);
  }

  // wave reduce + cross-wave via LDS + one atomic per block
#pragma unroll
  for (int off = 32; off > 0; off >>= 1) part += __shfl_down(part, off);
  if ((tid & 63) == 0) red[tid >> 6] = part;
  __syncthreads();
  if (tid == 0) atomicAdd(out, red[0] + red[1] + red[2]);
}

}  // namespace

extern "C" void kernel_launch(void* const* d_in, const int* in_sizes, int n_in,
                              void* d_out, int out_size, void* d_ws, size_t ws_size,
                              hipStream_t stream) {
  const float* params      = (const float*)d_in[0];
  const float* covp        = (const float*)d_in[1];
  const float* init_states = (const float*)d_in[2];
  const float* z           = (const float*)d_in[3];
  float* out = (float*)d_out;

  const size_t hist4B = (size_t)T * NT * sizeof(float4);  // 25.2 MB
  const size_t hist1B = (size_t)T * NT * sizeof(float);   //  6.3 MB
  const size_t aqB    = (size_t)T * NT * sizeof(float2);  // 12.6 MB
  const size_t needBytes = hist4B + hist1B + aqB;         // 44.1 MB

  hipMemsetAsync(d_out, 0, sizeof(float), stream);

  if (ws_size >= needBytes) {
    float4* hist4 = (float4*)d_ws;
    float*  hist1 = (float*)((char*)d_ws + hist4B);
    float2* aqp   = (float2*)((char*)d_ws + hist4B + hist1B);
    fused_kernel<<<NBLK, NTH, 0, stream>>>(params, covp, init_states, z,
                                           hist4, hist1, aqp, out);
  }
}